// Round 12
// baseline (212.456 us; speedup 1.0000x reference)
//
#include <hip/hip_runtime.h>
#include <stdint.h>

// Batched tiny MLP [B,13]->16->(30x 16->16 relu)->1, fp32 in/out, f16 MFMA.
// Transposed formulation: mfma D layout == B layout, so each layer's relu'd
// output is the next layer's B fragment in-register.
// R24: test the LEGACY-MFMA-quarter-rate theory. Seven kernels (R12..R23:
// schedules, occupancy 31-57%, memory paths, spill-free, asm-pinned regs)
// all sit at 43-45 cyc/SIMD/tile-layer. R23's VGPR_Count=52 with asm "v"
// pinning falsified the AGPR-bounce theory. Serial-issue accounting:
// 176k cyc = 39k VALU (4.75 instr/tile-layer, matches source) + ~5k ds/br
// + 132k MFMA => 32.3 cyc per legacy 16x16x16_f16 -- exactly a full-rate
// 32x32-class instruction's pipe time for QUARTER the FLOPs. The µbench
// table never measured the legacy K=16 shape (16x16 rows are the gfx950
// K=32 intrinsics). Hypothesis: carried-forward K=16 f16 runs at the old
// pass count => half-K half-rate. Fix: gfx950-native 16x16x32_f16 with
// upper K=16 zeroed: A = {W frag, 0}, B = {bf, 0} (doubled-K shapes are two
// stacked K=16 blocks: elems 0-3 <-> k=4g+i, elems 4-7 <-> k=16+4g+i, per
// ds_read_b64_tr_b16 layout evidence; C/D layout identical to legacy so
// bias riding in C, output row 0, and D->next-B chaining are unchanged).
// Body reverts to R18 fused form (schedule proven irrelevant). Regs ~65.
// Predictions: quarter-rate right => dispatch 50-58us; wrong => 76-84us
// and shape space closes (serial floor confirmed). absmax fail => K-block
// layout variant wrong, repack next round. WRITE_SIZE 8.2MB spill canary.
// Edge case: lane(col=15,g=3) k0=12 gather would read 2 dwords past x's end
// on the last tile (x is exactly 2097152*52B). That lane loads shifted by -3
// dwords and selects v[3] as k=12, zeros for k>=13.

typedef __attribute__((ext_vector_type(4))) _Float16 half4v;
typedef __attribute__((ext_vector_type(8))) _Float16 half8v;
typedef __attribute__((ext_vector_type(2))) _Float16 h2;
typedef __attribute__((ext_vector_type(4))) float float4v;

#define S_IN 13
#define H 16
#define NL 32            // mfma layers: 0 = input, 1..30 = hidden, 31 = output
#define TPB 512
#define WPB 8            // waves per block
#define T 8              // 16-sample tiles per wave per iteration
#define NBLOCKS 512      // fills 1024 SIMDs at 4 waves/SIMD
#define STRIDE (NBLOCKS * WPB * T)   // tiles per grid sweep = 32768

// LDS dword map (weights/bias only):
//   [0, 4096)     A-frags: 2 dwords (4 f16) per (L, lane)
//   [4096, 4608)  bias[L][m] fp32 (C-operand order)
#define LDS_DW 4608

__device__ __forceinline__ unsigned pkh(float a, float b) {
    return __builtin_bit_cast(unsigned, __builtin_amdgcn_cvt_pkrtz(a, b));
}

__device__ __forceinline__ half4v pack4h(float v0, float v1, float v2, float v3) {
    int2 p;
    p.x = (int)pkh(v0, v1);
    p.y = (int)pkh(v2, v3);
    return __builtin_bit_cast(half4v, p);
}

// cvt then packed-f16 relu: 2 cvt + 2 v_pk_max_f16
__device__ __forceinline__ half4v relu_pack4h(const float4v& d) {
    const h2 z = {(_Float16)0.f, (_Float16)0.f};
    h2 lo = __builtin_bit_cast(h2, pkh(d[0], d[1]));
    h2 hi = __builtin_bit_cast(h2, pkh(d[2], d[3]));
    lo = __builtin_elementwise_max(lo, z);
    hi = __builtin_elementwise_max(hi, z);
    int2 p;
    p.x = __builtin_bit_cast(int, lo);
    p.y = __builtin_bit_cast(int, hi);
    return __builtin_bit_cast(half4v, p);
}

// widen a K=16 fragment to the K=32 operand: lower block = frag, upper
// K-block = 0 (those A rows / B rows contribute nothing).
__device__ __forceinline__ half8v widen(half4v lo) {
    int2 l = __builtin_bit_cast(int2, lo);
    int4 q;
    q.x = l.x; q.y = l.y; q.z = 0; q.w = 0;
    return __builtin_bit_cast(half8v, q);
}

// align-4 16B load (tile rows are dword- but not 16B-aligned: stride 13 dw)
__device__ __forceinline__ float4v ld4u(const float* p) {
    float4v r;
    __builtin_memcpy(&r, p, 16);
    return r;
}

__global__ __launch_bounds__(TPB)
__attribute__((amdgpu_waves_per_eu(4, 4)))
void mlp_kernel(const float* __restrict__ x,
                const float* __restrict__ W_in, const float* __restrict__ b_in,
                const float* __restrict__ W_h,  const float* __restrict__ b_h,
                const float* __restrict__ W_out,const float* __restrict__ b_out,
                float* __restrict__ out, int tiles)
{
    __shared__ unsigned lds[LDS_DW];
    const int tid = threadIdx.x;

    // ---- swizzle weights into f16 A-fragment layout in LDS (once/block) ----
    for (int s = tid; s < NL * 64; s += TPB) {
        const int L = s >> 6, ln = s & 63, m = ln & 15, gg = ln >> 4;
        float v[4];
#pragma unroll
        for (int i = 0; i < 4; ++i) {
            const int k = 4 * gg + i;
            if (L == 0)       v[i] = (k < S_IN) ? W_in[m * S_IN + k] : 0.f;
            else if (L <= 30) v[i] = W_h[(L - 1) * H * H + m * H + k];
            else              v[i] = (m == 0) ? W_out[k] : 0.f;
        }
        lds[s * 2]     = pkh(v[0], v[1]);
        lds[s * 2 + 1] = pkh(v[2], v[3]);
    }
    for (int s = tid; s < NL * H; s += TPB) {
        const int L = s >> 4, m = s & 15;
        float bv;
        if (L == 0)       bv = b_in[m];
        else if (L <= 30) bv = b_h[(L - 1) * H + m];
        else              bv = (m == 0) ? b_out[0] : 0.f;
        lds[4096 + s] = __float_as_uint(bv);
    }
    __syncthreads();

    const half4v* lA = (const half4v*)lds;             // [NL*64], 8B elems
    const float4v* lB = (const float4v*)(lds + 4096);  // [NL*4]

    const int lane = tid & 63;
    const int wv   = tid >> 6;
    const int g    = lane >> 4;
    const int col  = lane & 15;
    const bool edge = (col == 15) && (g == 3);         // lane 63: k0=12 overshoot
    const int goff = col * 13 + 4 * g - (edge ? 3 : 0);

    const int wave_id = blockIdx.x * WPB + wv;
    int tb = wave_id * T;
    if (tb >= tiles) return;

    float* op = out + (size_t)tb * 16 + lane;

    for (; tb < tiles; tb += STRIDE) {
        // ---- gather + pack, two batches of 4 tiles (short live ranges) ----
        const float* xp = x + (size_t)tb * 208 + goff;
        half8v bf8[T];
#pragma unroll
        for (int half = 0; half < 2; ++half) {
            float4v v0 = ld4u(xp + (half * 4 + 0) * 208);
            float4v v1 = ld4u(xp + (half * 4 + 1) * 208);
            float4v v2 = ld4u(xp + (half * 4 + 2) * 208);
            float4v v3 = ld4u(xp + (half * 4 + 3) * 208);
            bf8[half * 4 + 0] = widen(pack4h(edge ? v0[3] : v0[0], edge ? 0.f : v0[1],
                                             edge ? 0.f : v0[2],  edge ? 0.f : v0[3]));
            bf8[half * 4 + 1] = widen(pack4h(edge ? v1[3] : v1[0], edge ? 0.f : v1[1],
                                             edge ? 0.f : v1[2],  edge ? 0.f : v1[3]));
            bf8[half * 4 + 2] = widen(pack4h(edge ? v2[3] : v2[0], edge ? 0.f : v2[1],
                                             edge ? 0.f : v2[2],  edge ? 0.f : v2[3]));
            bf8[half * 4 + 3] = widen(pack4h(edge ? v3[3] : v3[0], edge ? 0.f : v3[1],
                                             edge ? 0.f : v3[2],  edge ? 0.f : v3[3]));
        }

        // ---- layers 0..30: K=32 MFMA (upper K-block zero), fused relu ----
        half8v a8 = widen(lA[lane]);
        float4v cC = lB[g];
#pragma unroll 1
        for (int L = 0; L < NL - 1; ++L) {
            half4v aN = lA[(L + 1) * 64 + lane];
            float4v cN = lB[(L + 1) * 4 + g];
#pragma unroll
            for (int t = 0; t < T; ++t) {
                float4v d = __builtin_amdgcn_mfma_f32_16x16x32_f16(a8, bf8[t], cC, 0, 0, 0);
                bf8[t] = widen(relu_pack4h(d));
            }
            a8 = widen(aN);
            cC = cN;
        }

        // ---- output layer 31: W_out row 0 only; y[n] = D[0][n] ----
#pragma unroll
        for (int t = 0; t < T; ++t) {
            float4v d = __builtin_amdgcn_mfma_f32_16x16x32_f16(a8, bf8[t], cC, 0, 0, 0);
            if (lane < 16) op[t * 16] = d[0];
        }
        op += (size_t)STRIDE * 16;
    }
}

extern "C" void kernel_launch(void* const* d_in, const int* in_sizes, int n_in,
                              void* d_out, int out_size, void* d_ws, size_t ws_size,
                              hipStream_t stream) {
    const float* x     = (const float*)d_in[0];
    const float* W_in  = (const float*)d_in[1];
    const float* b_in  = (const float*)d_in[2];
    const float* W_h   = (const float*)d_in[3];
    const float* b_h   = (const float*)d_in[4];
    const float* W_out = (const float*)d_in[5];
    const float* b_out = (const float*)d_in[6];
    float* out = (float*)d_out;

    const int tiles = out_size / 16;                       // 131072
    int blocks = (tiles + WPB * T - 1) / (WPB * T);
    if (blocks > NBLOCKS) blocks = NBLOCKS;
    mlp_kernel<<<blocks, TPB, 0, stream>>>(x, W_in, b_in, W_h, b_h, W_out, b_out,
                                           out, tiles);
}